// Round 1
// baseline (318.508 us; speedup 1.0000x reference)
//
#include <hip/hip_runtime.h>
#include <hip/hip_bf16.h>
#include <cstdint>

// Problem constants
#define Bb 8
#define SLh 512
#define Hh 768
#define NSs 256
#define Ww 32
#define NHh 12
#define HDd 64
#define FFN_I 3072
#define NTOK (Bb*SLh)      // 4096
#define NSPAN (Bb*NSs)     // 2048

typedef __attribute__((ext_vector_type(8))) __bf16 bf16x8;
typedef __attribute__((ext_vector_type(4))) float f32x4;

__device__ __forceinline__ short f2bf(float f) {
  unsigned u = __builtin_bit_cast(unsigned, f);
  unsigned r = (u + 0x7fffu + ((u >> 16) & 1u)) >> 16;
  return (short)r;
}
__device__ __forceinline__ float bflo(unsigned u) { return __builtin_bit_cast(float, u << 16); }
__device__ __forceinline__ float bfhi(unsigned u) { return __builtin_bit_cast(float, u & 0xffff0000u); }

__device__ __forceinline__ void gload16(const void* g, void* l) {
  __builtin_amdgcn_global_load_lds(
      (__attribute__((address_space(1))) void*)(const_cast<void*>(g)),
      (__attribute__((address_space(3))) void*)l, 16, 0, 0);
}

// ---------------- tok = token_reps + pos_encoding, cast bf16 ----------------
__global__ __launch_bounds__(192) void tok_kernel(const float* __restrict__ tr,
                                                  short* __restrict__ tok) {
  int row = blockIdx.x;            // 4096 = b*512+s
  int s = row & (SLh - 1);
  int c0 = threadIdx.x * 4;        // 192 threads * 4 = 768
  float4 v = *(const float4*)(tr + (size_t)row * Hh + c0);
  const float kinv = -9.210340371976184f / (float)Hh;  // -ln(10000)/H
  float f0 = __expf((float)c0 * kinv);
  float f1 = __expf((float)(c0 + 2) * kinv);
  float s0, cc0, s1, cc1;
  __sincosf((float)s * f0, &s0, &cc0);
  __sincosf((float)s * f1, &s1, &cc1);
  v.x += s0; v.y += cc0; v.z += s1; v.w += cc1;
  short4 o{f2bf(v.x), f2bf(v.y), f2bf(v.z), f2bf(v.w)};
  *(short4*)(tok + (size_t)row * Hh + c0) = o;
}

// ---------------- generic f32 -> bf16 cast ----------------
__global__ __launch_bounds__(256) void castk(const float* __restrict__ in,
                                             short* __restrict__ out, int n4) {
  for (int i = blockIdx.x * 256 + threadIdx.x; i < n4; i += gridDim.x * 256) {
    float4 v = ((const float4*)in)[i];
    short4 o{f2bf(v.x), f2bf(v.y), f2bf(v.z), f2bf(v.w)};
    ((short4*)out)[i] = o;
  }
}

// ---------------- q vector (scaled 1/8) and bias2 = out_proj_b + q0 ----------------
__global__ __launch_bounds__(64) void prep_qb(const float* __restrict__ dq,
                                              const float* __restrict__ ipw,
                                              const float* __restrict__ ipb,
                                              const float* __restrict__ opb,
                                              float* __restrict__ qsv,
                                              float* __restrict__ bias2) {
  int h = blockIdx.x * 64 + threadIdx.x;   // 12 blocks * 64 = 768
  const float4* wr = (const float4*)(ipw + (size_t)h * Hh);  // Wq rows 0..767
  const float4* qv = (const float4*)dq;
  float acc = 0.f;
  for (int j = 0; j < Hh / 4; ++j) {
    float4 w4 = wr[j], q4 = qv[j];
    acc += w4.x * q4.x + w4.y * q4.y + w4.z * q4.z + w4.w * q4.w;
  }
  acc += ipb[h];
  qsv[h] = acc * 0.125f;          // / sqrt(64)
  bias2[h] = opb[h] + dq[h];
}

// ---------------- bf16 MFMA GEMM, C = A(MxK) * Bt(NxK)^T ----------------
// EPI 0: bf16 out = acc+bias ; 1: bf16 out = relu(acc+bias) ; 2: f32 out = acc+bias(+resid)
template <int EPI>
__global__ __launch_bounds__(256) void gemm_bt(const short* __restrict__ A,
                                               const short* __restrict__ Bt,
                                               const float* __restrict__ bias,
                                               const float* __restrict__ resid,
                                               float* __restrict__ Cf,
                                               short* __restrict__ Cb,
                                               int M, int N, int K) {
  __shared__ __align__(16) short Alds[128][32];
  __shared__ __align__(16) short Blds[128][32];
  const int tid = threadIdx.x;
  const int lane = tid & 63, wave = tid >> 6;
  const int wm = wave >> 1, wn = wave & 1;
  const int bx = blockIdx.x, by = blockIdx.y;   // bx->N, by->M
  const int row0 = by * 128, col0 = bx * 128;
  f32x4 acc[4][4] = {};
  const int nk = K >> 5;
  for (int kt = 0; kt < nk; ++kt) {
    const int k0 = kt * 32;
#pragma unroll
    for (int j = 0; j < 2; ++j) {
      int c = j * 256 + tid;            // 16B chunk id, row=c/4 col=(c&3)*8
      int uc = j * 256 + wave * 64;     // wave-uniform chunk base
      gload16(A + (size_t)(row0 + (c >> 2)) * K + k0 + (c & 3) * 8,
              &Alds[0][0] + uc * 8);
      gload16(Bt + (size_t)(col0 + (c >> 2)) * K + k0 + (c & 3) * 8,
              &Blds[0][0] + uc * 8);
    }
    __syncthreads();
    bf16x8 fa[4], fb[4];
#pragma unroll
    for (int i = 0; i < 4; ++i) {
      fa[i] = *(const bf16x8*)&Alds[wm * 64 + i * 16 + (lane & 15)][(lane >> 4) * 8];
      fb[i] = *(const bf16x8*)&Blds[wn * 64 + i * 16 + (lane & 15)][(lane >> 4) * 8];
    }
#pragma unroll
    for (int mi = 0; mi < 4; ++mi)
#pragma unroll
      for (int ni = 0; ni < 4; ++ni)
        acc[mi][ni] = __builtin_amdgcn_mfma_f32_16x16x32_bf16(fa[mi], fb[ni], acc[mi][ni], 0, 0, 0);
    __syncthreads();
  }
#pragma unroll
  for (int mi = 0; mi < 4; ++mi) {
#pragma unroll
    for (int ni = 0; ni < 4; ++ni) {
      int colb = col0 + wn * 64 + ni * 16 + (lane & 15);
      float bv = bias[colb];
#pragma unroll
      for (int r = 0; r < 4; ++r) {
        int rowb = row0 + wm * 64 + mi * 16 + (lane >> 4) * 4 + r;
        float v = acc[mi][ni][r] + bv;
        if (EPI == 1) v = fmaxf(v, 0.f);
        if (EPI == 2) {
          if (resid) v += resid[(size_t)rowb * N + colb];
          Cf[(size_t)rowb * N + colb] = v;
        } else {
          Cb[(size_t)rowb * N + colb] = f2bf(v);
        }
      }
    }
  }
}

// ---------------- per-span attention ----------------
// KV: 4096 x 1536 bf16 rows (K | V). ctx out: 2048 x 768 bf16.
__global__ __launch_bounds__(384) void attn_kernel(const short* __restrict__ KV,
                                                   const int* __restrict__ sid,
                                                   const float* __restrict__ qs,
                                                   short* __restrict__ ctx) {
  int n = blockIdx.x;
  int b = n >> 8;                       // NS=256
  __shared__ int posO[Ww];
  __shared__ float attnL[NHh][Ww];
  __shared__ int lenS;
  int tid = threadIdx.x;
  if (tid < Ww) {
    int st = sid[2 * n], en = sid[2 * n + 1];
    int p = st + tid;
    p = p < 0 ? 0 : (p > SLh - 1 ? SLh - 1 : p);
    posO[tid] = (b * SLh + p) * (2 * Hh);
    if (tid == 0) lenS = en - st;
  }
  __syncthreads();
  int len = lenS;
  int h = tid >> 5, w = tid & 31;       // 12*32 = 384
  // scores
  const int4* kr = (const int4*)(KV + posO[w] + h * HDd);
  const float4* qp = (const float4*)(qs + h * HDd);
  float acc = 0.f;
#pragma unroll
  for (int j = 0; j < 8; ++j) {
    int4 kk = kr[j];
    float4 qa = qp[2 * j], qb = qp[2 * j + 1];
    acc += qa.x * bflo(kk.x) + qa.y * bfhi(kk.x) + qa.z * bflo(kk.y) + qa.w * bfhi(kk.y);
    acc += qb.x * bflo(kk.z) + qb.y * bfhi(kk.z) + qb.z * bflo(kk.w) + qb.w * bfhi(kk.w);
  }
  float score = (w < len) ? acc : -1e9f;
  float m = score;
#pragma unroll
  for (int o = 16; o; o >>= 1) m = fmaxf(m, __shfl_xor(m, o, 32));
  float e = __expf(score - m);
  float ssum = e;
#pragma unroll
  for (int o = 16; o; o >>= 1) ssum += __shfl_xor(ssum, o, 32);
  attnL[h][w] = e / ssum;
  __syncthreads();
  // ctx: thread handles head hh, dim pair 2*dp
  int hh = tid >> 5, dp = tid & 31;
  float a0 = 0.f, a1 = 0.f;
#pragma unroll
  for (int w2 = 0; w2 < Ww; ++w2) {
    float aw = attnL[hh][w2];
    unsigned u = *(const unsigned*)(KV + posO[w2] + Hh + hh * HDd + 2 * dp);
    a0 += aw * bflo(u);
    a1 += aw * bfhi(u);
  }
  unsigned packed = (unsigned)(unsigned short)f2bf(a0) | ((unsigned)(unsigned short)f2bf(a1) << 16);
  ((unsigned*)ctx)[(size_t)n * (Hh / 2) + tid] = packed;
}

// ---------------- LayerNorm (row=768), out f32 + bf16 ----------------
__global__ __launch_bounds__(256) void ln_kernel(const float* __restrict__ Y,
                                                 const float* __restrict__ g,
                                                 const float* __restrict__ b,
                                                 float* __restrict__ xf,
                                                 short* __restrict__ xb) {
  int row = blockIdx.x;
  const float* y = Y + (size_t)row * Hh;
  int tid = threadIdx.x;
  float v[3]; float s1 = 0.f, s2 = 0.f;
#pragma unroll
  for (int i = 0; i < 3; ++i) { v[i] = y[tid + 256 * i]; s1 += v[i]; s2 += v[i] * v[i]; }
  __shared__ float r1[4], r2[4];
#pragma unroll
  for (int o = 32; o; o >>= 1) { s1 += __shfl_xor(s1, o); s2 += __shfl_xor(s2, o); }
  int lane = tid & 63, wv = tid >> 6;
  if (lane == 0) { r1[wv] = s1; r2[wv] = s2; }
  __syncthreads();
  s1 = r1[0] + r1[1] + r1[2] + r1[3];
  s2 = r2[0] + r2[1] + r2[2] + r2[3];
  float mu = s1 * (1.f / Hh);
  float var = s2 * (1.f / Hh) - mu * mu;
  float is = rsqrtf(var + 1e-5f);
#pragma unroll
  for (int i = 0; i < 3; ++i) {
    int c = tid + 256 * i;
    float o = (v[i] - mu) * is * g[c] + b[c];
    xf[(size_t)row * Hh + c] = o;
    xb[(size_t)row * Hh + c] = f2bf(o);
  }
}

// ---------------- final LayerNorm + zero-mask -> d_out (f32) ----------------
__global__ __launch_bounds__(256) void ln_final(const float* __restrict__ Y,
                                                const float* __restrict__ g,
                                                const float* __restrict__ b,
                                                const int* __restrict__ sid,
                                                float* __restrict__ out) {
  int row = blockIdx.x;
  int len = sid[2 * row + 1] - sid[2 * row];
  const float* y = Y + (size_t)row * Hh;
  int tid = threadIdx.x;
  float v[3]; float s1 = 0.f, s2 = 0.f;
#pragma unroll
  for (int i = 0; i < 3; ++i) { v[i] = y[tid + 256 * i]; s1 += v[i]; s2 += v[i] * v[i]; }
  __shared__ float r1[4], r2[4];
#pragma unroll
  for (int o = 32; o; o >>= 1) { s1 += __shfl_xor(s1, o); s2 += __shfl_xor(s2, o); }
  int lane = tid & 63, wv = tid >> 6;
  if (lane == 0) { r1[wv] = s1; r2[wv] = s2; }
  __syncthreads();
  s1 = r1[0] + r1[1] + r1[2] + r1[3];
  s2 = r2[0] + r2[1] + r2[2] + r2[3];
  float mu = s1 * (1.f / Hh);
  float var = s2 * (1.f / Hh) - mu * mu;
  float is = rsqrtf(var + 1e-5f);
  float keep = (len > 0) ? 1.f : 0.f;
#pragma unroll
  for (int i = 0; i < 3; ++i) {
    int c = tid + 256 * i;
    float o = ((v[i] - mu) * is * g[c] + b[c]) * keep;
    out[(size_t)row * Hh + c] = o;
  }
}

extern "C" void kernel_launch(void* const* d_in, const int* in_sizes, int n_in,
                              void* d_out, int out_size, void* d_ws, size_t ws_size,
                              hipStream_t stream) {
  const float* token_reps = (const float*)d_in[0];
  const int* span_ids = (const int*)d_in[1];
  const float* dq = (const float*)d_in[2];
  const float* ipw = (const float*)d_in[3];
  const float* ipb = (const float*)d_in[4];
  const float* opw = (const float*)d_in[5];
  const float* opb = (const float*)d_in[6];
  const float* lng = (const float*)d_in[7];
  const float* lnb = (const float*)d_in[8];
  const float* w1 = (const float*)d_in[9];
  const float* b1 = (const float*)d_in[10];
  const float* w2 = (const float*)d_in[11];
  const float* b2 = (const float*)d_in[12];
  float* out = (float*)d_out;

  char* p = (char*)d_ws;
  auto alloc = [&](size_t bytes) { void* r = p; p += (bytes + 255) & ~(size_t)255; return r; };
  short* tokb = (short*)alloc((size_t)NTOK * Hh * 2);
  short* kvw  = (short*)alloc((size_t)2 * Hh * Hh * 2);
  short* outw = (short*)alloc((size_t)Hh * Hh * 2);
  short* w1b  = (short*)alloc((size_t)FFN_I * Hh * 2);
  short* w2b  = (short*)alloc((size_t)Hh * FFN_I * 2);
  float* qsv  = (float*)alloc(Hh * 4);
  float* bias2= (float*)alloc(Hh * 4);
  short* KV   = (short*)alloc((size_t)NTOK * 2 * Hh * 2);
  short* ctxb = (short*)alloc((size_t)NSPAN * Hh * 2);
  float* attnY= (float*)alloc((size_t)NSPAN * Hh * 4);
  float* xf   = (float*)alloc((size_t)NSPAN * Hh * 4);
  short* xb   = (short*)alloc((size_t)NSPAN * Hh * 2);
  short* hb   = (short*)alloc((size_t)NSPAN * FFN_I * 2);
  float* y2   = (float*)alloc((size_t)NSPAN * Hh * 4);

  // 1. tok = token_reps + pe  (bf16)
  tok_kernel<<<NTOK, 192, 0, stream>>>(token_reps, tokb);
  // 2. weight casts
  castk<<<1152, 256, 0, stream>>>(ipw + (size_t)Hh * Hh, kvw, 2 * Hh * Hh / 4);
  castk<<<576, 256, 0, stream>>>(opw, outw, Hh * Hh / 4);
  castk<<<2048, 256, 0, stream>>>(w1, w1b, FFN_I * Hh / 4);
  castk<<<2048, 256, 0, stream>>>(w2, w2b, Hh * FFN_I / 4);
  // 3. q vector + combined bias
  prep_qb<<<12, 64, 0, stream>>>(dq, ipw, ipb, opb, qsv, bias2);
  // 4. KV = tok @ [Wk;Wv]^T + [bk;bv]   (4096 x 1536)
  gemm_bt<0><<<dim3(12, 32), 256, 0, stream>>>(tokb, kvw, ipb + Hh, nullptr,
                                               nullptr, KV, NTOK, 2 * Hh, Hh);
  // 5. per-span attention -> ctx
  attn_kernel<<<NSPAN, 384, 0, stream>>>(KV, span_ids, qsv, ctxb);
  // 6. attn_out = ctx @ Wo^T + bo + q0  (f32)
  gemm_bt<2><<<dim3(6, 16), 256, 0, stream>>>(ctxb, outw, bias2, nullptr,
                                              attnY, nullptr, NSPAN, Hh, Hh);
  // 7. x = LN(attn_out)
  ln_kernel<<<NSPAN, 256, 0, stream>>>(attnY, lng, lnb, xf, xb);
  // 8. h = relu(x @ W1^T + b1)  (bf16)
  gemm_bt<1><<<dim3(24, 16), 256, 0, stream>>>(xb, w1b, b1, nullptr,
                                               nullptr, hb, NSPAN, FFN_I, Hh);
  // 9. y2 = h @ W2^T + b2 + x  (f32)
  gemm_bt<2><<<dim3(6, 16), 256, 0, stream>>>(hb, w2b, b2, xf,
                                              y2, nullptr, NSPAN, Hh, FFN_I);
  // 10. out = LN(y2) masked by len>0
  ln_final<<<NSPAN, 256, 0, stream>>>(y2, lng, lnb, span_ids, out);
}

// Round 2
// 285.758 us; speedup vs baseline: 1.1146x; 1.1146x over previous
//
#include <hip/hip_runtime.h>
#include <hip/hip_bf16.h>
#include <cstdint>

// Problem constants
#define Bb 8
#define SLh 512
#define Hh 768
#define NSs 256
#define Ww 32
#define NHh 12
#define HDd 64
#define FFN_I 3072
#define NTOK (Bb*SLh)      // 4096
#define NSPAN (Bb*NSs)     // 2048

typedef __attribute__((ext_vector_type(8))) __bf16 bf16x8;
typedef __attribute__((ext_vector_type(4))) float f32x4;

__device__ __forceinline__ short f2bf(float f) {
  unsigned u = __builtin_bit_cast(unsigned, f);
  unsigned r = (u + 0x7fffu + ((u >> 16) & 1u)) >> 16;
  return (short)r;
}
__device__ __forceinline__ float bflo(unsigned u) { return __builtin_bit_cast(float, u << 16); }
__device__ __forceinline__ float bfhi(unsigned u) { return __builtin_bit_cast(float, u & 0xffff0000u); }

__device__ __forceinline__ void gload16(const void* g, void* l) {
  __builtin_amdgcn_global_load_lds(
      (__attribute__((address_space(1))) void*)(const_cast<void*>(g)),
      (__attribute__((address_space(3))) void*)l, 16, 0, 0);
}

// ---------------- tok = token_reps + pos_encoding, cast bf16 ----------------
__global__ __launch_bounds__(192) void tok_kernel(const float* __restrict__ tr,
                                                  short* __restrict__ tok) {
  int row = blockIdx.x;            // 4096 = b*512+s
  int s = row & (SLh - 1);
  int c0 = threadIdx.x * 4;        // 192 threads * 4 = 768
  float4 v = *(const float4*)(tr + (size_t)row * Hh + c0);
  const float kinv = -9.210340371976184f / (float)Hh;  // -ln(10000)/H
  float f0 = __expf((float)c0 * kinv);
  float f1 = __expf((float)(c0 + 2) * kinv);
  float s0, cc0, s1, cc1;
  __sincosf((float)s * f0, &s0, &cc0);
  __sincosf((float)s * f1, &s1, &cc1);
  v.x += s0; v.y += cc0; v.z += s1; v.w += cc1;
  short4 o{f2bf(v.x), f2bf(v.y), f2bf(v.z), f2bf(v.w)};
  *(short4*)(tok + (size_t)row * Hh + c0) = o;
}

// ---------------- generic f32 -> bf16 cast ----------------
__global__ __launch_bounds__(256) void castk(const float* __restrict__ in,
                                             short* __restrict__ out, int n4) {
  for (int i = blockIdx.x * 256 + threadIdx.x; i < n4; i += gridDim.x * 256) {
    float4 v = ((const float4*)in)[i];
    short4 o{f2bf(v.x), f2bf(v.y), f2bf(v.z), f2bf(v.w)};
    ((short4*)out)[i] = o;
  }
}

// ---------------- q vector (scaled 1/8) and bias2 = out_proj_b + q0 ----------------
__global__ __launch_bounds__(64) void prep_qb(const float* __restrict__ dq,
                                              const float* __restrict__ ipw,
                                              const float* __restrict__ ipb,
                                              const float* __restrict__ opb,
                                              float* __restrict__ qsv,
                                              float* __restrict__ bias2) {
  int h = blockIdx.x * 64 + threadIdx.x;   // 12 blocks * 64 = 768
  const float4* wr = (const float4*)(ipw + (size_t)h * Hh);  // Wq rows 0..767
  const float4* qv = (const float4*)dq;
  float acc = 0.f;
  for (int j = 0; j < Hh / 4; ++j) {
    float4 w4 = wr[j], q4 = qv[j];
    acc += w4.x * q4.x + w4.y * q4.y + w4.z * q4.z + w4.w * q4.w;
  }
  acc += ipb[h];
  qsv[h] = acc * 0.125f;          // / sqrt(64)
  bias2[h] = opb[h] + dq[h];
}

// ---------------- bf16 MFMA GEMM, C = A(MxK) * Bt(NxK)^T ----------------
// 128x128 tile, BK=64, double-buffered LDS, counted-vmcnt 2-phase pipeline.
// LDS layout XOR-swizzled (slot ^= row&7) via pre-swizzled global source
// (linear DMA dest) + swizzled ds_read (rule #21 / m201 pattern).
// EPI 0: bf16 out = acc+bias ; 1: bf16 out = relu(acc+bias) ; 2: f32 out = acc+bias(+resid)
template <int EPI>
__global__ __launch_bounds__(256, 2) void gemm_bt(const short* __restrict__ A,
                                                  const short* __restrict__ Bt,
                                                  const float* __restrict__ bias,
                                                  const float* __restrict__ resid,
                                                  float* __restrict__ Cf,
                                                  short* __restrict__ Cb,
                                                  int M, int N, int K) {
  __shared__ __align__(16) short Alds[2][128][64];   // 16 KB per buffer
  __shared__ __align__(16) short Blds[2][128][64];   // total 64 KB
  const int tid = threadIdx.x;
  const int lane = tid & 63, wave = tid >> 6;
  const int wm = wave >> 1, wn = wave & 1;
  const int row0 = blockIdx.y * 128, col0 = blockIdx.x * 128;
  const int l15 = lane & 15, hi = lane >> 4, sx = l15 & 7;
  f32x4 acc[4][4] = {};
  const int nk = K >> 6;

  // stage K-tile kt into buffer bi. chunk c (16B): row=c>>3, dest slot=c&7.
  // data for dest slot sd of row r comes from global col-chunk sd ^ (r&7).
  auto stage = [&](int kt, int bi) {
#pragma unroll
    for (int j = 0; j < 4; ++j) {
      int c = j * 256 + tid;                    // 0..1023
      int row = c >> 3;
      int colc = ((c & 7) ^ (row & 7)) * 8;     // swizzled source col (elements)
      int uc = j * 256 + wave * 64;             // wave-uniform chunk base
      gload16(A + (size_t)(row0 + row) * K + kt * 64 + colc,
              (char*)&Alds[bi][0][0] + (size_t)uc * 16);
      gload16(Bt + (size_t)(col0 + row) * K + kt * 64 + colc,
              (char*)&Blds[bi][0][0] + (size_t)uc * 16);
    }
  };

  stage(0, 0);
  for (int kt = 0; kt < nk; ++kt) {
    const int cur = kt & 1;
    if (kt + 1 < nk) {
      stage(kt + 1, cur ^ 1);                       // prefetch next tile
      asm volatile("s_waitcnt vmcnt(8)" ::: "memory");  // wait only stage(kt)
    } else {
      asm volatile("s_waitcnt vmcnt(0)" ::: "memory");
    }
    __builtin_amdgcn_s_barrier();                   // buf cur ready everywhere
    asm volatile("" ::: "memory");
    bf16x8 fa[2][4], fb[2][4];
#pragma unroll
    for (int kk = 0; kk < 2; ++kk) {
      const int so = ((kk * 4 + hi) ^ sx) * 16;     // swizzled slot byte off
#pragma unroll
      for (int i = 0; i < 4; ++i) {
        fa[kk][i] = *(const bf16x8*)((const char*)&Alds[cur][0][0] +
                                     (size_t)(wm * 64 + i * 16 + l15) * 128 + so);
        fb[kk][i] = *(const bf16x8*)((const char*)&Blds[cur][0][0] +
                                     (size_t)(wn * 64 + i * 16 + l15) * 128 + so);
      }
    }
#pragma unroll
    for (int mi = 0; mi < 4; ++mi)
#pragma unroll
      for (int ni = 0; ni < 4; ++ni) {
        acc[mi][ni] = __builtin_amdgcn_mfma_f32_16x16x32_bf16(fa[0][mi], fb[0][ni], acc[mi][ni], 0, 0, 0);
        acc[mi][ni] = __builtin_amdgcn_mfma_f32_16x16x32_bf16(fa[1][mi], fb[1][ni], acc[mi][ni], 0, 0, 0);
      }
    asm volatile("" ::: "memory");
    __builtin_amdgcn_s_barrier();                   // reads of cur done -> may overwrite
  }
#pragma unroll
  for (int mi = 0; mi < 4; ++mi) {
#pragma unroll
    for (int ni = 0; ni < 4; ++ni) {
      int colb = col0 + wn * 64 + ni * 16 + (lane & 15);
      float bv = bias[colb];
#pragma unroll
      for (int r = 0; r < 4; ++r) {
        int rowb = row0 + wm * 64 + mi * 16 + (lane >> 4) * 4 + r;
        float v = acc[mi][ni][r] + bv;
        if (EPI == 1) v = fmaxf(v, 0.f);
        if (EPI == 2) {
          if (resid) v += resid[(size_t)rowb * N + colb];
          Cf[(size_t)rowb * N + colb] = v;
        } else {
          Cb[(size_t)rowb * N + colb] = f2bf(v);
        }
      }
    }
  }
}

// ---------------- per-span attention ----------------
// KV: 4096 x 1536 bf16 rows (K | V). ctx out: 2048 x 768 bf16.
__global__ __launch_bounds__(384) void attn_kernel(const short* __restrict__ KV,
                                                   const int* __restrict__ sid,
                                                   const float* __restrict__ qs,
                                                   short* __restrict__ ctx) {
  int n = blockIdx.x;
  int b = n >> 8;                       // NS=256
  __shared__ int posO[Ww];
  __shared__ float attnL[NHh][Ww];
  __shared__ int lenS;
  int tid = threadIdx.x;
  if (tid < Ww) {
    int st = sid[2 * n], en = sid[2 * n + 1];
    int p = st + tid;
    p = p < 0 ? 0 : (p > SLh - 1 ? SLh - 1 : p);
    posO[tid] = (b * SLh + p) * (2 * Hh);
    if (tid == 0) lenS = en - st;
  }
  __syncthreads();
  int len = lenS;
  int h = tid >> 5, w = tid & 31;       // 12*32 = 384
  // scores
  const int4* kr = (const int4*)(KV + posO[w] + h * HDd);
  const float4* qp = (const float4*)(qs + h * HDd);
  float acc = 0.f;
#pragma unroll
  for (int j = 0; j < 8; ++j) {
    int4 kk = kr[j];
    float4 qa = qp[2 * j], qb = qp[2 * j + 1];
    acc += qa.x * bflo(kk.x) + qa.y * bfhi(kk.x) + qa.z * bflo(kk.y) + qa.w * bfhi(kk.y);
    acc += qb.x * bflo(kk.z) + qb.y * bfhi(kk.z) + qb.z * bflo(kk.w) + qb.w * bfhi(kk.w);
  }
  float score = (w < len) ? acc : -1e9f;
  float m = score;
#pragma unroll
  for (int o = 16; o; o >>= 1) m = fmaxf(m, __shfl_xor(m, o, 32));
  float e = __expf(score - m);
  float ssum = e;
#pragma unroll
  for (int o = 16; o; o >>= 1) ssum += __shfl_xor(ssum, o, 32);
  attnL[h][w] = e / ssum;
  __syncthreads();
  // ctx: thread handles head hh, dim pair 2*dp
  int hh = tid >> 5, dp = tid & 31;
  float a0 = 0.f, a1 = 0.f;
#pragma unroll
  for (int w2 = 0; w2 < Ww; ++w2) {
    float aw = attnL[hh][w2];
    unsigned u = *(const unsigned*)(KV + posO[w2] + Hh + hh * HDd + 2 * dp);
    a0 += aw * bflo(u);
    a1 += aw * bfhi(u);
  }
  unsigned packed = (unsigned)(unsigned short)f2bf(a0) | ((unsigned)(unsigned short)f2bf(a1) << 16);
  ((unsigned*)ctx)[(size_t)n * (Hh / 2) + tid] = packed;
}

// ---------------- LayerNorm (row=768), out f32 + bf16 ----------------
__global__ __launch_bounds__(256) void ln_kernel(const float* __restrict__ Y,
                                                 const float* __restrict__ g,
                                                 const float* __restrict__ b,
                                                 float* __restrict__ xf,
                                                 short* __restrict__ xb) {
  int row = blockIdx.x;
  const float* y = Y + (size_t)row * Hh;
  int tid = threadIdx.x;
  float v[3]; float s1 = 0.f, s2 = 0.f;
#pragma unroll
  for (int i = 0; i < 3; ++i) { v[i] = y[tid + 256 * i]; s1 += v[i]; s2 += v[i] * v[i]; }
  __shared__ float r1[4], r2[4];
#pragma unroll
  for (int o = 32; o; o >>= 1) { s1 += __shfl_xor(s1, o); s2 += __shfl_xor(s2, o); }
  int lane = tid & 63, wv = tid >> 6;
  if (lane == 0) { r1[wv] = s1; r2[wv] = s2; }
  __syncthreads();
  s1 = r1[0] + r1[1] + r1[2] + r1[3];
  s2 = r2[0] + r2[1] + r2[2] + r2[3];
  float mu = s1 * (1.f / Hh);
  float var = s2 * (1.f / Hh) - mu * mu;
  float is = rsqrtf(var + 1e-5f);
#pragma unroll
  for (int i = 0; i < 3; ++i) {
    int c = tid + 256 * i;
    float o = (v[i] - mu) * is * g[c] + b[c];
    xf[(size_t)row * Hh + c] = o;
    xb[(size_t)row * Hh + c] = f2bf(o);
  }
}

// ---------------- final LayerNorm + zero-mask -> d_out (f32) ----------------
__global__ __launch_bounds__(256) void ln_final(const float* __restrict__ Y,
                                                const float* __restrict__ g,
                                                const float* __restrict__ b,
                                                const int* __restrict__ sid,
                                                float* __restrict__ out) {
  int row = blockIdx.x;
  int len = sid[2 * row + 1] - sid[2 * row];
  const float* y = Y + (size_t)row * Hh;
  int tid = threadIdx.x;
  float v[3]; float s1 = 0.f, s2 = 0.f;
#pragma unroll
  for (int i = 0; i < 3; ++i) { v[i] = y[tid + 256 * i]; s1 += v[i]; s2 += v[i] * v[i]; }
  __shared__ float r1[4], r2[4];
#pragma unroll
  for (int o = 32; o; o >>= 1) { s1 += __shfl_xor(s1, o); s2 += __shfl_xor(s2, o); }
  int lane = tid & 63, wv = tid >> 6;
  if (lane == 0) { r1[wv] = s1; r2[wv] = s2; }
  __syncthreads();
  s1 = r1[0] + r1[1] + r1[2] + r1[3];
  s2 = r2[0] + r2[1] + r2[2] + r2[3];
  float mu = s1 * (1.f / Hh);
  float var = s2 * (1.f / Hh) - mu * mu;
  float is = rsqrtf(var + 1e-5f);
  float keep = (len > 0) ? 1.f : 0.f;
#pragma unroll
  for (int i = 0; i < 3; ++i) {
    int c = tid + 256 * i;
    float o = ((v[i] - mu) * is * g[c] + b[c]) * keep;
    out[(size_t)row * Hh + c] = o;
  }
}

extern "C" void kernel_launch(void* const* d_in, const int* in_sizes, int n_in,
                              void* d_out, int out_size, void* d_ws, size_t ws_size,
                              hipStream_t stream) {
  const float* token_reps = (const float*)d_in[0];
  const int* span_ids = (const int*)d_in[1];
  const float* dq = (const float*)d_in[2];
  const float* ipw = (const float*)d_in[3];
  const float* ipb = (const float*)d_in[4];
  const float* opw = (const float*)d_in[5];
  const float* opb = (const float*)d_in[6];
  const float* lng = (const float*)d_in[7];
  const float* lnb = (const float*)d_in[8];
  const float* w1 = (const float*)d_in[9];
  const float* b1 = (const float*)d_in[10];
  const float* w2 = (const float*)d_in[11];
  const float* b2 = (const float*)d_in[12];
  float* out = (float*)d_out;

  char* p = (char*)d_ws;
  auto alloc = [&](size_t bytes) { void* r = p; p += (bytes + 255) & ~(size_t)255; return r; };
  short* tokb = (short*)alloc((size_t)NTOK * Hh * 2);
  short* kvw  = (short*)alloc((size_t)2 * Hh * Hh * 2);
  short* outw = (short*)alloc((size_t)Hh * Hh * 2);
  short* w1b  = (short*)alloc((size_t)FFN_I * Hh * 2);
  short* w2b  = (short*)alloc((size_t)Hh * FFN_I * 2);
  float* qsv  = (float*)alloc(Hh * 4);
  float* bias2= (float*)alloc(Hh * 4);
  short* KV   = (short*)alloc((size_t)NTOK * 2 * Hh * 2);
  short* ctxb = (short*)alloc((size_t)NSPAN * Hh * 2);
  float* attnY= (float*)alloc((size_t)NSPAN * Hh * 4);
  float* xf   = (float*)alloc((size_t)NSPAN * Hh * 4);
  short* xb   = (short*)alloc((size_t)NSPAN * Hh * 2);
  short* hb   = (short*)alloc((size_t)NSPAN * FFN_I * 2);
  float* y2   = (float*)alloc((size_t)NSPAN * Hh * 4);

  // 1. tok = token_reps + pe  (bf16)
  tok_kernel<<<NTOK, 192, 0, stream>>>(token_reps, tokb);
  // 2. weight casts
  castk<<<1152, 256, 0, stream>>>(ipw + (size_t)Hh * Hh, kvw, 2 * Hh * Hh / 4);
  castk<<<576, 256, 0, stream>>>(opw, outw, Hh * Hh / 4);
  castk<<<2048, 256, 0, stream>>>(w1, w1b, FFN_I * Hh / 4);
  castk<<<2048, 256, 0, stream>>>(w2, w2b, Hh * FFN_I / 4);
  // 3. q vector + combined bias
  prep_qb<<<12, 64, 0, stream>>>(dq, ipw, ipb, opb, qsv, bias2);
  // 4. KV = tok @ [Wk;Wv]^T + [bk;bv]   (4096 x 1536)
  gemm_bt<0><<<dim3(12, 32), 256, 0, stream>>>(tokb, kvw, ipb + Hh, nullptr,
                                               nullptr, KV, NTOK, 2 * Hh, Hh);
  // 5. per-span attention -> ctx
  attn_kernel<<<NSPAN, 384, 0, stream>>>(KV, span_ids, qsv, ctxb);
  // 6. attn_out = ctx @ Wo^T + bo + q0  (f32)
  gemm_bt<2><<<dim3(6, 16), 256, 0, stream>>>(ctxb, outw, bias2, nullptr,
                                              attnY, nullptr, NSPAN, Hh, Hh);
  // 7. x = LN(attn_out)
  ln_kernel<<<NSPAN, 256, 0, stream>>>(attnY, lng, lnb, xf, xb);
  // 8. h = relu(x @ W1^T + b1)  (bf16)
  gemm_bt<1><<<dim3(24, 16), 256, 0, stream>>>(xb, w1b, b1, nullptr,
                                               nullptr, hb, NSPAN, FFN_I, Hh);
  // 9. y2 = h @ W2^T + b2 + x  (f32)
  gemm_bt<2><<<dim3(6, 16), 256, 0, stream>>>(hb, w2b, b2, xf,
                                              y2, nullptr, NSPAN, Hh, FFN_I);
  // 10. out = LN(y2) masked by len>0
  ln_final<<<NSPAN, 256, 0, stream>>>(y2, lng, lnb, span_ids, out);
}

// Round 3
// 254.812 us; speedup vs baseline: 1.2500x; 1.1214x over previous
//
#include <hip/hip_runtime.h>
#include <hip/hip_bf16.h>
#include <cstdint>

// Problem constants
#define Bb 8
#define SLh 512
#define Hh 768
#define NSs 256
#define Ww 32
#define NHh 12
#define HDd 64
#define FFN_I 3072
#define NTOK (Bb*SLh)      // 4096
#define NSPAN (Bb*NSs)     // 2048

typedef __attribute__((ext_vector_type(8))) __bf16 bf16x8;
typedef __attribute__((ext_vector_type(4))) float f32x4;

__device__ __forceinline__ short f2bf(float f) {
  unsigned u = __builtin_bit_cast(unsigned, f);
  unsigned r = (u + 0x7fffu + ((u >> 16) & 1u)) >> 16;
  return (short)r;
}
__device__ __forceinline__ float bflo(unsigned u) { return __builtin_bit_cast(float, u << 16); }
__device__ __forceinline__ float bfhi(unsigned u) { return __builtin_bit_cast(float, u & 0xffff0000u); }

__device__ __forceinline__ void gload16(const void* g, void* l) {
  __builtin_amdgcn_global_load_lds(
      (__attribute__((address_space(1))) void*)(const_cast<void*>(g)),
      (__attribute__((address_space(3))) void*)l, 16, 0, 0);
}

// ---------------- tok = token_reps + pos_encoding, cast bf16 ----------------
__global__ __launch_bounds__(192) void tok_kernel(const float* __restrict__ tr,
                                                  short* __restrict__ tok) {
  int row = blockIdx.x;            // 4096 = b*512+s
  int s = row & (SLh - 1);
  int c0 = threadIdx.x * 4;        // 192 threads * 4 = 768
  float4 v = *(const float4*)(tr + (size_t)row * Hh + c0);
  const float kinv = -9.210340371976184f / (float)Hh;  // -ln(10000)/H
  float f0 = __expf((float)c0 * kinv);
  float f1 = __expf((float)(c0 + 2) * kinv);
  float s0, cc0, s1, cc1;
  __sincosf((float)s * f0, &s0, &cc0);
  __sincosf((float)s * f1, &s1, &cc1);
  v.x += s0; v.y += cc0; v.z += s1; v.w += cc1;
  short4 o{f2bf(v.x), f2bf(v.y), f2bf(v.z), f2bf(v.w)};
  *(short4*)(tok + (size_t)row * Hh + c0) = o;
}

// ---------------- fused f32 -> bf16 cast of the 4 weight matrices ----------------
// block ranges: [0,1152) kv (294912 f4), [1152,1728) out (147456),
//               [1728,4032) w1 (589824), [4032,6336) w2 (589824)
__global__ __launch_bounds__(256) void cast4(const float* __restrict__ s0,
                                             const float* __restrict__ s1,
                                             const float* __restrict__ s2,
                                             const float* __restrict__ s3,
                                             short* __restrict__ d0,
                                             short* __restrict__ d1,
                                             short* __restrict__ d2,
                                             short* __restrict__ d3) {
  int b = blockIdx.x;
  const float* s; short* d; int off;
  if (b < 1152)      { s = s0; d = d0; off = b; }
  else if (b < 1728) { s = s1; d = d1; off = b - 1152; }
  else if (b < 4032) { s = s2; d = d2; off = b - 1728; }
  else               { s = s3; d = d3; off = b - 4032; }
  int i = off * 256 + threadIdx.x;
  float4 v = ((const float4*)s)[i];
  short4 o{f2bf(v.x), f2bf(v.y), f2bf(v.z), f2bf(v.w)};
  ((short4*)d)[i] = o;
}

// ---------------- q vector (scaled 1/8) and bias2 = out_proj_b + q0 ----------------
__global__ __launch_bounds__(64) void prep_qb(const float* __restrict__ dq,
                                              const float* __restrict__ ipw,
                                              const float* __restrict__ ipb,
                                              const float* __restrict__ opb,
                                              float* __restrict__ qsv,
                                              float* __restrict__ bias2) {
  int h = blockIdx.x * 64 + threadIdx.x;   // 12 blocks * 64 = 768
  const float4* wr = (const float4*)(ipw + (size_t)h * Hh);  // Wq rows 0..767
  const float4* qv = (const float4*)dq;
  float acc = 0.f;
  for (int j = 0; j < Hh / 4; ++j) {
    float4 w4 = wr[j], q4 = qv[j];
    acc += w4.x * q4.x + w4.y * q4.y + w4.z * q4.z + w4.w * q4.w;
  }
  acc += ipb[h];
  qsv[h] = acc * 0.125f;          // / sqrt(64)
  bias2[h] = opb[h] + dq[h];
}

// ---------------- bf16 MFMA GEMM, C = A(MxK) * Bt(NxK)^T ----------------
// 128x128 tile, BK=64, 512 threads (8 waves 2Mx4N), 3-stage LDS pipeline
// (96 KB), counted vmcnt. XOR-swizzled LDS via pre-swizzled global source
// (linear DMA dest) + swizzled ds_read (rule #21 / m201 pattern).
// EPI 0: bf16 = acc+bias ; 1: bf16 = relu(acc+bias) ; 2: f32 = acc+bias ;
// EPI 3: f32 partial = acc, blockIdx.z selects Cf (z=0) / Cf2 (z=1).
template <int EPI>
__global__ __launch_bounds__(512, 1) void gemm_bt(const short* __restrict__ A,
                                                  const short* __restrict__ Bt,
                                                  const float* __restrict__ bias,
                                                  float* __restrict__ Cf,
                                                  float* __restrict__ Cf2,
                                                  short* __restrict__ Cb,
                                                  int M, int N, int ldk, int Kc) {
  __shared__ __align__(16) short Alds[3][128][64];   // 16 KB per stage
  __shared__ __align__(16) short Blds[3][128][64];   // total 96 KB
  const int tid = threadIdx.x;
  const int lane = tid & 63, wave = tid >> 6;
  const int wm = wave >> 2, wn = wave & 3;           // 2 x 4 wave grid
  const int row0 = blockIdx.y * 128, col0 = blockIdx.x * 128;
  const int kbase = blockIdx.z * Kc;
  const int l15 = lane & 15, hi = lane >> 4;
  f32x4 acc[4][2] = {};
  const int nk = Kc >> 6;

  // stage K-tile kt into stage buffer st. chunk c (16B): row=c>>3, slot=c&7.
  // dest slot sd of row r is fed from global col-chunk sd ^ (r&7).
  auto stage = [&](int kt, int st) {
#pragma unroll
    for (int j = 0; j < 2; ++j) {
      int c = j * 512 + tid;                    // 0..1023
      int row = c >> 3;
      int colc = ((c & 7) ^ (row & 7)) * 8;     // swizzled source col (elems)
      int uc = j * 512 + wave * 64;             // wave-uniform chunk base
      gload16(A + (size_t)(row0 + row) * ldk + kbase + kt * 64 + colc,
              (char*)&Alds[st][0][0] + (size_t)uc * 16);
      gload16(Bt + (size_t)(col0 + row) * ldk + kbase + kt * 64 + colc,
              (char*)&Blds[st][0][0] + (size_t)uc * 16);
    }
  };

  stage(0, 0);
  if (nk > 1) stage(1, 1);
  int st = 0;
  for (int kt = 0; kt < nk; ++kt) {
    if (kt + 2 < nk) {
      int st2 = st + 2; if (st2 >= 3) st2 -= 3;
      stage(kt + 2, st2);                              // prefetch 2 ahead
      asm volatile("s_waitcnt vmcnt(8)" ::: "memory"); // stage kt done (4/wave)
    } else if (kt + 1 < nk) {
      asm volatile("s_waitcnt vmcnt(4)" ::: "memory");
    } else {
      asm volatile("s_waitcnt vmcnt(0)" ::: "memory");
    }
    __builtin_amdgcn_s_barrier();                      // buf st ready everywhere
    asm volatile("" ::: "memory");
    bf16x8 fa[2][4], fb[2][2];
#pragma unroll
    for (int kk = 0; kk < 2; ++kk) {
      const int s = kk * 4 + hi;                       // logical 16B slot
#pragma unroll
      for (int i = 0; i < 4; ++i) {
        int R = wm * 64 + i * 16 + l15;
        fa[kk][i] = *(const bf16x8*)((const char*)&Alds[st][0][0] +
                                     (size_t)R * 128 + ((s ^ (R & 7)) * 16));
      }
#pragma unroll
      for (int i = 0; i < 2; ++i) {
        int R = wn * 32 + i * 16 + l15;
        fb[kk][i] = *(const bf16x8*)((const char*)&Blds[st][0][0] +
                                     (size_t)R * 128 + ((s ^ (R & 7)) * 16));
      }
    }
#pragma unroll
    for (int kk = 0; kk < 2; ++kk)
#pragma unroll
      for (int mi = 0; mi < 4; ++mi)
#pragma unroll
        for (int ni = 0; ni < 2; ++ni)
          acc[mi][ni] = __builtin_amdgcn_mfma_f32_16x16x32_bf16(fa[kk][mi], fb[kk][ni], acc[mi][ni], 0, 0, 0);
    asm volatile("" ::: "memory");
    __builtin_amdgcn_s_barrier();                      // reads of st done
    if (++st >= 3) st = 0;
  }
  float* dst = (EPI == 3) ? (blockIdx.z ? Cf2 : Cf) : Cf;
#pragma unroll
  for (int mi = 0; mi < 4; ++mi) {
#pragma unroll
    for (int ni = 0; ni < 2; ++ni) {
      int colb = col0 + wn * 32 + ni * 16 + l15;
      float bv = (EPI < 3) ? bias[colb] : 0.f;
#pragma unroll
      for (int r = 0; r < 4; ++r) {
        int rowb = row0 + wm * 64 + mi * 16 + hi * 4 + r;
        float v = acc[mi][ni][r] + bv;
        if (EPI == 1) v = fmaxf(v, 0.f);
        if (EPI >= 2) {
          dst[(size_t)rowb * N + colb] = v;
        } else {
          Cb[(size_t)rowb * N + colb] = f2bf(v);
        }
      }
    }
  }
}

// ---------------- per-span attention ----------------
// KV: 4096 x 1536 bf16 rows (K | V). ctx out: 2048 x 768 bf16.
__global__ __launch_bounds__(384) void attn_kernel(const short* __restrict__ KV,
                                                   const int* __restrict__ sid,
                                                   const float* __restrict__ qs,
                                                   short* __restrict__ ctx) {
  int n = blockIdx.x;
  int b = n >> 8;                       // NS=256
  __shared__ int posO[Ww];
  __shared__ float attnL[NHh][Ww];
  __shared__ int lenS;
  int tid = threadIdx.x;
  if (tid < Ww) {
    int st = sid[2 * n], en = sid[2 * n + 1];
    int p = st + tid;
    p = p < 0 ? 0 : (p > SLh - 1 ? SLh - 1 : p);
    posO[tid] = (b * SLh + p) * (2 * Hh);
    if (tid == 0) lenS = en - st;
  }
  __syncthreads();
  int len = lenS;
  int h = tid >> 5, w = tid & 31;       // 12*32 = 384
  const int4* kr = (const int4*)(KV + posO[w] + h * HDd);
  const float4* qp = (const float4*)(qs + h * HDd);
  float acc = 0.f;
#pragma unroll
  for (int j = 0; j < 8; ++j) {
    int4 kk = kr[j];
    float4 qa = qp[2 * j], qb = qp[2 * j + 1];
    acc += qa.x * bflo(kk.x) + qa.y * bfhi(kk.x) + qa.z * bflo(kk.y) + qa.w * bfhi(kk.y);
    acc += qb.x * bflo(kk.z) + qb.y * bfhi(kk.z) + qb.z * bflo(kk.w) + qb.w * bfhi(kk.w);
  }
  float score = (w < len) ? acc : -1e9f;
  float m = score;
#pragma unroll
  for (int o = 16; o; o >>= 1) m = fmaxf(m, __shfl_xor(m, o, 32));
  float e = __expf(score - m);
  float ssum = e;
#pragma unroll
  for (int o = 16; o; o >>= 1) ssum += __shfl_xor(ssum, o, 32);
  attnL[h][w] = e / ssum;
  __syncthreads();
  int hh = tid >> 5, dp = tid & 31;
  float a0 = 0.f, a1 = 0.f;
#pragma unroll
  for (int w2 = 0; w2 < Ww; ++w2) {
    float aw = attnL[hh][w2];
    unsigned u = *(const unsigned*)(KV + posO[w2] + Hh + hh * HDd + 2 * dp);
    a0 += aw * bflo(u);
    a1 += aw * bfhi(u);
  }
  unsigned packed = (unsigned)(unsigned short)f2bf(a0) | ((unsigned)(unsigned short)f2bf(a1) << 16);
  ((unsigned*)ctx)[(size_t)n * (Hh / 2) + tid] = packed;
}

// ---------------- LayerNorm (row=768), out f32 + bf16 ----------------
__global__ __launch_bounds__(256) void ln_kernel(const float* __restrict__ Y,
                                                 const float* __restrict__ g,
                                                 const float* __restrict__ b,
                                                 float* __restrict__ xf,
                                                 short* __restrict__ xb) {
  int row = blockIdx.x;
  const float* y = Y + (size_t)row * Hh;
  int tid = threadIdx.x;
  float v[3]; float s1 = 0.f, s2 = 0.f;
#pragma unroll
  for (int i = 0; i < 3; ++i) { v[i] = y[tid + 256 * i]; s1 += v[i]; s2 += v[i] * v[i]; }
  __shared__ float r1[4], r2[4];
#pragma unroll
  for (int o = 32; o; o >>= 1) { s1 += __shfl_xor(s1, o); s2 += __shfl_xor(s2, o); }
  int lane = tid & 63, wv = tid >> 6;
  if (lane == 0) { r1[wv] = s1; r2[wv] = s2; }
  __syncthreads();
  s1 = r1[0] + r1[1] + r1[2] + r1[3];
  s2 = r2[0] + r2[1] + r2[2] + r2[3];
  float mu = s1 * (1.f / Hh);
  float var = s2 * (1.f / Hh) - mu * mu;
  float is = rsqrtf(var + 1e-5f);
#pragma unroll
  for (int i = 0; i < 3; ++i) {
    int c = tid + 256 * i;
    float o = (v[i] - mu) * is * g[c] + b[c];
    xf[(size_t)row * Hh + c] = o;
    xb[(size_t)row * Hh + c] = f2bf(o);
  }
}

// ---------------- final LN over (y2a + y2b + b2 + x) + zero-mask ----------------
__global__ __launch_bounds__(256) void ln_final(const float* __restrict__ Ya,
                                                const float* __restrict__ Yb,
                                                const float* __restrict__ b2,
                                                const float* __restrict__ xf,
                                                const float* __restrict__ g,
                                                const float* __restrict__ b,
                                                const int* __restrict__ sid,
                                                float* __restrict__ out) {
  int row = blockIdx.x;
  int len = sid[2 * row + 1] - sid[2 * row];
  int tid = threadIdx.x;
  float v[3]; float s1 = 0.f, s2 = 0.f;
#pragma unroll
  for (int i = 0; i < 3; ++i) {
    int c = tid + 256 * i;
    size_t idx = (size_t)row * Hh + c;
    v[i] = Ya[idx] + Yb[idx] + b2[c] + xf[idx];
    s1 += v[i]; s2 += v[i] * v[i];
  }
  __shared__ float r1[4], r2[4];
#pragma unroll
  for (int o = 32; o; o >>= 1) { s1 += __shfl_xor(s1, o); s2 += __shfl_xor(s2, o); }
  int lane = tid & 63, wv = tid >> 6;
  if (lane == 0) { r1[wv] = s1; r2[wv] = s2; }
  __syncthreads();
  s1 = r1[0] + r1[1] + r1[2] + r1[3];
  s2 = r2[0] + r2[1] + r2[2] + r2[3];
  float mu = s1 * (1.f / Hh);
  float var = s2 * (1.f / Hh) - mu * mu;
  float is = rsqrtf(var + 1e-5f);
  float keep = (len > 0) ? 1.f : 0.f;
#pragma unroll
  for (int i = 0; i < 3; ++i) {
    int c = tid + 256 * i;
    float o = ((v[i] - mu) * is * g[c] + b[c]) * keep;
    out[(size_t)row * Hh + c] = o;
  }
}

extern "C" void kernel_launch(void* const* d_in, const int* in_sizes, int n_in,
                              void* d_out, int out_size, void* d_ws, size_t ws_size,
                              hipStream_t stream) {
  const float* token_reps = (const float*)d_in[0];
  const int* span_ids = (const int*)d_in[1];
  const float* dq = (const float*)d_in[2];
  const float* ipw = (const float*)d_in[3];
  const float* ipb = (const float*)d_in[4];
  const float* opw = (const float*)d_in[5];
  const float* opb = (const float*)d_in[6];
  const float* lng = (const float*)d_in[7];
  const float* lnb = (const float*)d_in[8];
  const float* w1 = (const float*)d_in[9];
  const float* b1 = (const float*)d_in[10];
  const float* w2 = (const float*)d_in[11];
  const float* b2 = (const float*)d_in[12];
  float* out = (float*)d_out;

  char* p = (char*)d_ws;
  auto alloc = [&](size_t bytes) { void* r = p; p += (bytes + 255) & ~(size_t)255; return r; };
  short* tokb = (short*)alloc((size_t)NTOK * Hh * 2);
  short* kvw  = (short*)alloc((size_t)2 * Hh * Hh * 2);
  short* outw = (short*)alloc((size_t)Hh * Hh * 2);
  short* w1b  = (short*)alloc((size_t)FFN_I * Hh * 2);
  short* w2b  = (short*)alloc((size_t)Hh * FFN_I * 2);
  float* qsv  = (float*)alloc(Hh * 4);
  float* bias2= (float*)alloc(Hh * 4);
  short* KV   = (short*)alloc((size_t)NTOK * 2 * Hh * 2);
  short* ctxb = (short*)alloc((size_t)NSPAN * Hh * 2);
  float* attnY= (float*)alloc((size_t)NSPAN * Hh * 4);   // also FFN2 partial z=1
  float* xf   = (float*)alloc((size_t)NSPAN * Hh * 4);
  short* xb   = (short*)alloc((size_t)NSPAN * Hh * 2);
  short* hb   = (short*)alloc((size_t)NSPAN * FFN_I * 2);
  float* y2   = (float*)alloc((size_t)NSPAN * Hh * 4);   // FFN2 partial z=0

  // 1. tok = token_reps + pe  (bf16)
  tok_kernel<<<NTOK, 192, 0, stream>>>(token_reps, tokb);
  // 2. fused weight casts
  cast4<<<6336, 256, 0, stream>>>(ipw + (size_t)Hh * Hh, opw, w1, w2,
                                  kvw, outw, w1b, w2b);
  // 3. q vector + combined bias
  prep_qb<<<12, 64, 0, stream>>>(dq, ipw, ipb, opb, qsv, bias2);
  // 4. KV = tok @ [Wk;Wv]^T + [bk;bv]   (4096 x 1536 bf16)
  gemm_bt<0><<<dim3(12, 32, 1), 512, 0, stream>>>(tokb, kvw, ipb + Hh,
                                                  nullptr, nullptr, KV,
                                                  NTOK, 2 * Hh, Hh, Hh);
  // 5. per-span attention -> ctx
  attn_kernel<<<NSPAN, 384, 0, stream>>>(KV, span_ids, qsv, ctxb);
  // 6. attn_out = ctx @ Wo^T + (bo + q0)  (f32)
  gemm_bt<2><<<dim3(6, 16, 1), 512, 0, stream>>>(ctxb, outw, bias2,
                                                 attnY, nullptr, nullptr,
                                                 NSPAN, Hh, Hh, Hh);
  // 7. x = LN(attn_out)
  ln_kernel<<<NSPAN, 256, 0, stream>>>(attnY, lng, lnb, xf, xb);
  // 8. h = relu(x @ W1^T + b1)  (bf16)
  gemm_bt<1><<<dim3(24, 16, 1), 512, 0, stream>>>(xb, w1b, b1,
                                                  nullptr, nullptr, hb,
                                                  NSPAN, FFN_I, Hh, Hh);
  // 9. y2 partials = h @ W2^T  (split-K=2; z=0 -> y2, z=1 -> attnY reuse)
  gemm_bt<3><<<dim3(6, 16, 2), 512, 0, stream>>>(hb, w2b, nullptr,
                                                 y2, attnY, nullptr,
                                                 NSPAN, Hh, FFN_I, FFN_I / 2);
  // 10. out = LN(y2a + y2b + b2 + x) masked by len>0
  ln_final<<<NSPAN, 256, 0, stream>>>(y2, attnY, b2, xf, lng, lnb, span_ids, out);
}